// Round 6
// baseline (232.889 us; speedup 1.0000x reference)
//
#include <hip/hip_runtime.h>
#include <math.h>

#define NB 10
#define NCLS 100
#define RPT 64          // rows per tile (1e6 = 64 * 15625, exact)
#define LSTR 104        // LDS row stride (floats): 16B-aligned, 4-way banks max
#define TILE_F4 1600    // float4 chunks per tile

// Double-buffered LDS pipeline: issue next tile's global loads (regs) ->
// compute current tile from LDS -> ds_write next tile into other buffer.
// One barrier per tile; load latency hides under ~500cy of exp/fmax compute.
// Compute path and accumulation identical to R4 (absmax 0.0).
__global__ __launch_bounds__(256) void ece_main(const float* __restrict__ outputs,
                                                const int* __restrict__ targets,
                                                double* __restrict__ gacc,
                                                int nrows) {
    __shared__ float tile[2][RPT * LSTR];     // 2 x 26.6 KB
    __shared__ float s_cnt[NB], s_sp[NB], s_sc[NB];

    const int tid = threadIdx.x;
    if (tid < NB) { s_cnt[tid] = 0.f; s_sp[tid] = 0.f; s_sc[tid] = 0.f; }

    const int r_loc = tid >> 2;               // row within tile
    const int q     = tid & 3;                // quarter within row
    const int ntiles = nrows / RPT;           // 15625, exact

    // tile-invariant LDS float-offsets for my 7 staging chunks
    int wofs[7];
    #pragma unroll
    for (int k = 0; k < 7; ++k) {
        const int f = tid + 256 * k;
        wofs[k] = (f / 25) * LSTR + (f % 25) * 4;
    }

    int ti = blockIdx.x;
    if (ti < ntiles) {
        float4 st[7];
        int tmy;

        // prologue: stage tile ti into buf 0
        {
            const float4* __restrict__ src =
                reinterpret_cast<const float4*>(outputs) + (size_t)ti * TILE_F4;
            #pragma unroll
            for (int k = 0; k < 7; ++k) {
                const int f = tid + 256 * k;
                if (f < TILE_F4) st[k] = src[f];
            }
            tmy = targets[ti * RPT + r_loc];
            #pragma unroll
            for (int k = 0; k < 7; ++k) {
                const int f = tid + 256 * k;
                if (f < TILE_F4)
                    *reinterpret_cast<float4*>(&tile[0][wofs[k]]) = st[k];
            }
        }

        int cur = 0;
        while (ti < ntiles) {
            const int  tnext   = ti + gridDim.x;
            const bool hasnext = tnext < ntiles;

            __syncthreads();   // buf[cur] writes visible; buf[cur^1] free

            // issue prefetch loads for tnext (in flight across compute)
            int tnxt_my = 0;
            if (hasnext) {
                const float4* __restrict__ src =
                    reinterpret_cast<const float4*>(outputs) + (size_t)tnext * TILE_F4;
                #pragma unroll
                for (int k = 0; k < 7; ++k) {
                    const int f = tid + 256 * k;
                    if (f < TILE_F4) st[k] = src[f];
                }
                tnxt_my = targets[tnext * RPT + r_loc];
            }

            // ---- compute tile ti from LDS buf[cur] (verified R4 path) ----
            {
                const float* __restrict__ L = &tile[cur][r_loc * LSTR];
                float4 v[6];
                #pragma unroll
                for (int k = 0; k < 6; ++k)
                    v[k] = *reinterpret_cast<const float4*>(&L[q * 4 + k * 16]);
                const float tail = L[96 + q];
                const int t = tmy;

                // local (max, argcol), first occurrence = lowest col wins
                float m = v[0].x;
                int   c = q * 4;
                #pragma unroll
                for (int k = 0; k < 6; ++k) {
                    const int base = k * 16 + q * 4;
                    if (k > 0 && v[k].x > m) { m = v[k].x; c = base; }
                    if (v[k].y > m) { m = v[k].y; c = base + 1; }
                    if (v[k].z > m) { m = v[k].z; c = base + 2; }
                    if (v[k].w > m) { m = v[k].w; c = base + 3; }
                }
                if (tail > m) { m = tail; c = 96 + q; }

                #pragma unroll
                for (int off = 1; off <= 2; off <<= 1) {
                    const float om = __shfl_xor(m, off);
                    const int   oc = __shfl_xor(c, off);
                    if (om > m || (om == m && oc < c)) { m = om; c = oc; }
                }

                float s = 0.f, te = 0.f;
                #pragma unroll
                for (int k = 0; k < 6; ++k) {
                    const int base = k * 16 + q * 4;
                    const float e0 = __expf(v[k].x - m);
                    const float e1 = __expf(v[k].y - m);
                    const float e2 = __expf(v[k].z - m);
                    const float e3 = __expf(v[k].w - m);
                    s += (e0 + e1) + (e2 + e3);
                    if (base     == t) te = e0;
                    if (base + 1 == t) te = e1;
                    if (base + 2 == t) te = e2;
                    if (base + 3 == t) te = e3;
                }
                {
                    const float et = __expf(tail - m);
                    s += et;
                    if (96 + q == t) te = et;
                }
                #pragma unroll
                for (int off = 1; off <= 2; off <<= 1) {
                    s  += __shfl_xor(s, off);
                    te += __shfl_xor(te, off);
                }

                if (q == 0) {
                    const float p = te / s;                    // in (0, 1]
                    const float corr = (c == t) ? 1.0f : 0.0f;
                    const float b[NB + 1] = {0.0f, 0.1f, 0.2f, 0.3f, 0.4f, 0.5f,
                                             0.6f, 0.7f, 0.8f, 0.9f, 1.0f};
                    int j = 0;
                    #pragma unroll
                    for (int k = 0; k <= NB; ++k) j += (b[k] < p) ? 1 : 0;
                    int bin = j - 1;
                    if (bin >= 0) {
                        if (bin > NB - 1) bin = NB - 1;
                        atomicAdd(&s_cnt[bin], 1.0f);
                        atomicAdd(&s_sp[bin], p);
                        atomicAdd(&s_sc[bin], corr);
                    }
                }
            }
            // ---- end compute ----

            // write prefetched tile into the other buffer
            if (hasnext) {
                #pragma unroll
                for (int k = 0; k < 7; ++k) {
                    const int f = tid + 256 * k;
                    if (f < TILE_F4)
                        *reinterpret_cast<float4*>(&tile[cur ^ 1][wofs[k]]) = st[k];
                }
                tmy = tnxt_my;
            }

            cur ^= 1;
            ti = tnext;
        }
    }

    __syncthreads();
    if (tid < NB) {
        atomicAdd(&gacc[tid],          (double)s_cnt[tid]);
        atomicAdd(&gacc[NB + tid],     (double)s_sp[tid]);
        atomicAdd(&gacc[2 * NB + tid], (double)s_sc[tid]);
    }
}

__global__ void ece_final(const double* __restrict__ gacc, float* __restrict__ out) {
    if (threadIdx.x == 0 && blockIdx.x == 0) {
        double ece = 0.0, total = 0.0;
        for (int i = 0; i < NB; ++i) {
            const double c = gacc[i];
            if (c > 0.0) {
                const double ap = gacc[NB + i] / c;
                const double ac = gacc[2 * NB + i] / c;
                ece += c * fabs(ap - ac);
                total += c;
            }
        }
        out[0] = (total > 0.0) ? (float)(ece / total) : 0.0f;
    }
}

extern "C" void kernel_launch(void* const* d_in, const int* in_sizes, int n_in,
                              void* d_out, int out_size, void* d_ws, size_t ws_size,
                              hipStream_t stream) {
    const float* outputs = (const float*)d_in[0];
    const int*   targets = (const int*)d_in[1];
    float* out   = (float*)d_out;
    double* gacc = (double*)d_ws;

    const int nrows = in_sizes[1];  // 1,000,000

    hipMemsetAsync(gacc, 0, 3 * NB * sizeof(double), stream);

    const int blocks = 2048;  // 15625 tiles, 7-8 per block; 3 blocks/CU (LDS)
    ece_main<<<blocks, 256, 0, stream>>>(outputs, targets, gacc, nrows);
    ece_final<<<1, 64, 0, stream>>>(gacc, out);
}

// Round 7
// 124.607 us; speedup vs baseline: 1.8690x; 1.8690x over previous
//
#include <hip/hip_runtime.h>
#include <math.h>

#define NB 10
#define NCLS 100
#define RPT 64            // rows per tile; 1e6 = 64 * 15625 exact
#define TILE_F  (RPT * NCLS)      // 6400 floats = 25.6 KB
#define TILE_F4 (TILE_F / 4)      // 1600 float4
#define NCHUNK  (TILE_F4 / 64)    // 25 x 1KB wave chunks

// Double-buffered LDS pipeline staged via global_load_lds (async DMA, zero
// VGPR cost -> no scratch spill, unlike R6's reg-staging which wrote 370MB
// of spill traffic). Linear LDS layout (100-float row stride) as required by
// the DMA's lane-linear destination. Compute = R4's verified 4-lane-per-row
// path. fp32 LDS partials -> double global atomics -> fp64 finalize.
__global__ __launch_bounds__(256) void ece_main(const float* __restrict__ outputs,
                                                const int* __restrict__ targets,
                                                double* __restrict__ gacc,
                                                int nrows) {
    __shared__ float tile[2][TILE_F];         // 2 x 25.6 KB, linear
    __shared__ float s_cnt[NB], s_sp[NB], s_sc[NB];

    const int tid = threadIdx.x;
    if (tid < NB) { s_cnt[tid] = 0.f; s_sp[tid] = 0.f; s_sc[tid] = 0.f; }

    const int lane  = tid & 63;
    const int wid   = tid >> 6;
    const int r_loc = tid >> 2;               // row within tile
    const int q     = tid & 3;                // quarter within row
    const int ntiles = nrows / RPT;           // 15625 for 1e6
    const int rem    = nrows - ntiles * RPT;  // 0 for 1e6

    const float4* __restrict__ src4 = reinterpret_cast<const float4*>(outputs);

    int ti = blockIdx.x;
    if (ti < ntiles) {
        int tmy;
        // prologue: stage tile ti into buf 0 via DMA
        #pragma unroll
        for (int k = 0; k < 7; ++k) {
            const int c = wid * 7 + k;        // 1KB chunk id
            if (c < NCHUNK) {
                const float4* g = src4 + (size_t)ti * TILE_F4 + c * 64 + lane;
                __builtin_amdgcn_global_load_lds(
                    (const __attribute__((address_space(1))) void*)g,
                    (__attribute__((address_space(3))) void*)&tile[0][c * 256],
                    16, 0, 0);
            }
        }
        tmy = targets[ti * RPT + r_loc];
        __syncthreads();                      // drains vmcnt(0) + barrier

        int cur = 0;
        while (ti < ntiles) {
            const int  tnext   = ti + gridDim.x;
            const bool hasnext = tnext < ntiles;

            // stage next tile into the other buffer (async, hides under compute)
            int tn = 0;
            if (hasnext) {
                #pragma unroll
                for (int k = 0; k < 7; ++k) {
                    const int c = wid * 7 + k;
                    if (c < NCHUNK) {
                        const float4* g = src4 + (size_t)tnext * TILE_F4 + c * 64 + lane;
                        __builtin_amdgcn_global_load_lds(
                            (const __attribute__((address_space(1))) void*)g,
                            (__attribute__((address_space(3))) void*)&tile[cur ^ 1][c * 256],
                            16, 0, 0);
                    }
                }
                tn = targets[tnext * RPT + r_loc];
            }

            // ---- compute tile ti from LDS buf[cur] (verified R4 path) ----
            {
                const float* __restrict__ L = &tile[cur][r_loc * NCLS];
                float4 v[6];
                #pragma unroll
                for (int k = 0; k < 6; ++k)
                    v[k] = *reinterpret_cast<const float4*>(&L[q * 4 + k * 16]);
                const float tail = L[96 + q];
                const int t = tmy;

                float m = v[0].x;
                int   c = q * 4;
                #pragma unroll
                for (int k = 0; k < 6; ++k) {
                    const int base = k * 16 + q * 4;
                    if (k > 0 && v[k].x > m) { m = v[k].x; c = base; }
                    if (v[k].y > m) { m = v[k].y; c = base + 1; }
                    if (v[k].z > m) { m = v[k].z; c = base + 2; }
                    if (v[k].w > m) { m = v[k].w; c = base + 3; }
                }
                if (tail > m) { m = tail; c = 96 + q; }

                #pragma unroll
                for (int off = 1; off <= 2; off <<= 1) {
                    const float om = __shfl_xor(m, off);
                    const int   oc = __shfl_xor(c, off);
                    if (om > m || (om == m && oc < c)) { m = om; c = oc; }
                }

                float s = 0.f, te = 0.f;
                #pragma unroll
                for (int k = 0; k < 6; ++k) {
                    const int base = k * 16 + q * 4;
                    const float e0 = __expf(v[k].x - m);
                    const float e1 = __expf(v[k].y - m);
                    const float e2 = __expf(v[k].z - m);
                    const float e3 = __expf(v[k].w - m);
                    s += (e0 + e1) + (e2 + e3);
                    if (base     == t) te = e0;
                    if (base + 1 == t) te = e1;
                    if (base + 2 == t) te = e2;
                    if (base + 3 == t) te = e3;
                }
                {
                    const float et = __expf(tail - m);
                    s += et;
                    if (96 + q == t) te = et;
                }
                #pragma unroll
                for (int off = 1; off <= 2; off <<= 1) {
                    s  += __shfl_xor(s, off);
                    te += __shfl_xor(te, off);
                }

                if (q == 0) {
                    const float p = te / s;                    // in (0, 1]
                    const float corr = (c == t) ? 1.0f : 0.0f;
                    const float b[NB + 1] = {0.0f, 0.1f, 0.2f, 0.3f, 0.4f, 0.5f,
                                             0.6f, 0.7f, 0.8f, 0.9f, 1.0f};
                    int j = 0;
                    #pragma unroll
                    for (int k = 0; k <= NB; ++k) j += (b[k] < p) ? 1 : 0;
                    int bin = j - 1;
                    if (bin >= 0) {
                        if (bin > NB - 1) bin = NB - 1;
                        atomicAdd(&s_cnt[bin], 1.0f);
                        atomicAdd(&s_sp[bin], p);
                        atomicAdd(&s_sc[bin], corr);
                    }
                }
            }
            // ---- end compute ----

            __syncthreads();    // drains prefetch DMA (vmcnt 0) + barrier
            cur ^= 1;
            tmy = tn;
            ti = tnext;
        }
    }

    // leftover rows (nrows % 64 != 0) — never taken for BATCH=1e6
    if (rem > 0 && blockIdx.x == 0 && tid < rem) {
        const int r = ntiles * RPT + tid;
        const float* R = outputs + (size_t)r * NCLS;
        float m = R[0];
        int   c = 0;
        for (int j = 1; j < NCLS; ++j) { const float x = R[j]; if (x > m) { m = x; c = j; } }
        float s = 0.f;
        for (int j = 0; j < NCLS; ++j) s += __expf(R[j] - m);
        const int t = targets[r];
        const float p = __expf(R[t] - m) / s;
        const float corr = (c == t) ? 1.0f : 0.0f;
        const float b[NB + 1] = {0.0f, 0.1f, 0.2f, 0.3f, 0.4f, 0.5f,
                                 0.6f, 0.7f, 0.8f, 0.9f, 1.0f};
        int j = 0;
        for (int k = 0; k <= NB; ++k) j += (b[k] < p) ? 1 : 0;
        int bin = j - 1;
        if (bin >= 0) {
            if (bin > NB - 1) bin = NB - 1;
            atomicAdd(&s_cnt[bin], 1.0f);
            atomicAdd(&s_sp[bin], p);
            atomicAdd(&s_sc[bin], corr);
        }
    }

    __syncthreads();
    if (tid < NB) {
        atomicAdd(&gacc[tid],          (double)s_cnt[tid]);
        atomicAdd(&gacc[NB + tid],     (double)s_sp[tid]);
        atomicAdd(&gacc[2 * NB + tid], (double)s_sc[tid]);
    }
}

__global__ void ece_final(const double* __restrict__ gacc, float* __restrict__ out) {
    if (threadIdx.x == 0 && blockIdx.x == 0) {
        double ece = 0.0, total = 0.0;
        for (int i = 0; i < NB; ++i) {
            const double c = gacc[i];
            if (c > 0.0) {
                const double ap = gacc[NB + i] / c;
                const double ac = gacc[2 * NB + i] / c;
                ece += c * fabs(ap - ac);
                total += c;
            }
        }
        out[0] = (total > 0.0) ? (float)(ece / total) : 0.0f;
    }
}

extern "C" void kernel_launch(void* const* d_in, const int* in_sizes, int n_in,
                              void* d_out, int out_size, void* d_ws, size_t ws_size,
                              hipStream_t stream) {
    const float* outputs = (const float*)d_in[0];
    const int*   targets = (const int*)d_in[1];
    float* out   = (float*)d_out;
    double* gacc = (double*)d_ws;

    const int nrows = in_sizes[1];  // 1,000,000

    hipMemsetAsync(gacc, 0, 3 * NB * sizeof(double), stream);

    const int blocks = 2048;  // 15625 tiles, 7-8 per block; 3 blocks/CU (LDS)
    ece_main<<<blocks, 256, 0, stream>>>(outputs, targets, gacc, nrows);
    ece_final<<<1, 64, 0, stream>>>(gacc, out);
}